// Round 14
// baseline (184.936 us; speedup 1.0000x reference)
//
#include <hip/hip_runtime.h>
#include <hip/hip_bf16.h>
#include <stdint.h>

// ---------------- types ----------------
typedef __attribute__((ext_vector_type(8))) short    bf16x8;
typedef __attribute__((ext_vector_type(4))) float    f32x4;
typedef __attribute__((ext_vector_type(8))) unsigned short u16x8;
typedef __attribute__((ext_vector_type(4))) unsigned short u16x4;
typedef __attribute__((ext_vector_type(8))) _Float16 f16x8;

#define N_TOK   4096
#define C_DIM   768
#define NCLU    32
#define ZSPLIT  8

// RNE float->bf16
__device__ __forceinline__ uint16_t f2bf(float f){
  union { float f; unsigned u; } v; v.f = f;
  unsigned r = v.u + 0x7fffu + ((v.u >> 16) & 1u);
  return (uint16_t)(r >> 16);
}

__device__ __forceinline__ void gl2lds16(const void* g, void* l){
  __builtin_amdgcn_global_load_lds(
      (const __attribute__((address_space(1))) unsigned int*)g,
      (__attribute__((address_space(3))) unsigned int*)l, 16, 0, 0);
}

// ---------------- 2) per-cluster sums: LDS accumulate + atomic flush into csum ----------------
__global__ __launch_bounds__(256) void csum_part_k(const float* __restrict__ x, const int* __restrict__ idx,
                                                   float* __restrict__ csum){
  __shared__ float lacc[NCLU * 256];
  __shared__ int   sidx[32];
  const int tc = blockIdx.x, chunk = blockIdx.y;
  const int tid = threadIdx.x;
  #pragma unroll
  for (int u = 0; u < NCLU; ++u) lacc[u * 256 + tid] = 0.f;
  if (tid < 32) sidx[tid] = idx[tc * 32 + tid];
  __syncthreads();
  const int ch = chunk * 256 + tid;
  const float* xb = x + (size_t)(tc * 32) * C_DIM + ch;
  #pragma unroll 8
  for (int t = 0; t < 32; ++t){
    int c = sidx[t];                         // wave-uniform broadcast
    lacc[c * 256 + tid] += xb[(size_t)t * C_DIM];
  }
  __syncthreads();
  float* cb = csum + chunk * 256 + tid;
  #pragma unroll
  for (int c = 0; c < NCLU; ++c) atomicAdd(cb + (size_t)c * C_DIM, lacc[c * 256 + tid]);
}

// ---------------- 3) proxy/key l2norm -> bf16  (+ resize tail, blocks >= 1024) ----------------
// Blocks [0,1024): one token per WAVE (4/block); chunked-XCD remap so each XCD owns a
// contiguous 512-token span -> neighbor-row gathers (i±1, i±32) hit that XCD's L2.
// Blocks [1024,2560): bilinear resize 24x24 -> 32x32 of v_ext into Vt[h*64+d][n] bf16.
__global__ __launch_bounds__(256) void proxy_key_k(const float* __restrict__ x, const int* __restrict__ idx,
                                                   const float* __restrict__ csum,
                                                   uint16_t* __restrict__ An, uint16_t* __restrict__ Bn,
                                                   const float* __restrict__ vext,
                                                   uint16_t* __restrict__ Vt){
  __shared__ float ld[64 * 33];                    // resize scratch (8448 B)
  const int tid = threadIdx.x;

  if (blockIdx.x >= 1024){
    // ---- resize: block rb -> (bh, y) ----
    const int rb = (int)blockIdx.x - 1024, bh = rb >> 5, y = rb & 31;
    const int b = bh / 12, h = bh % 12;
    const float* base = vext + (size_t)bh * 576 * 64;
    float sy = (y + 0.5f) * 0.75f - 0.5f;
    float fy0 = floorf(sy); float fy = sy - fy0; int y0 = (int)fy0;
    int iy0 = y0 < 0 ? 0 : y0;  int iy1 = (y0 + 1 > 23) ? 23 : y0 + 1;
    const int d = tid & 63, xg = tid >> 6;
    #pragma unroll
    for (int jj = 0; jj < 8; ++jj){
      int xx = xg + 4 * jj;
      float sx = (xx + 0.5f) * 0.75f - 0.5f;
      float fx0 = floorf(sx); float fx = sx - fx0; int x0 = (int)fx0;
      int ix0 = x0 < 0 ? 0 : x0;  int ix1 = (x0 + 1 > 23) ? 23 : x0 + 1;
      float v00 = base[(iy0 * 24 + ix0) * 64 + d];
      float v01 = base[(iy0 * 24 + ix1) * 64 + d];
      float v10 = base[(iy1 * 24 + ix0) * 64 + d];
      float v11 = base[(iy1 * 24 + ix1) * 64 + d];
      ld[d * 33 + xx] = (1.f - fy) * ((1.f - fx) * v00 + fx * v01)
                      +        fy  * ((1.f - fx) * v10 + fx * v11);
    }
    __syncthreads();
    const int xx = tid & 31, dg = tid >> 5;
    const int n = b * 1024 + y * 32 + xx;
    #pragma unroll
    for (int jj = 0; jj < 8; ++jj){
      int d2 = dg * 8 + jj;
      Vt[(size_t)(h * 64 + d2) * 4096 + n] = f2bf(ld[d2 * 33 + xx]);
    }
    return;
  }

  const int bid = (int)blockIdx.x;
  const int tb  = ((bid & 7) << 7) + (bid >> 3);   // chunked XCD swizzle (bijective on [0,1024))
  const int i = tb * 4 + (tid >> 6);
  const int lane = tid & 63;
  const int ci = idx[i];
  const int b = i >> 10, s = i & 1023, r = s >> 5, w = s & 31;
  const int drs[8] = {-1,-1,-1, 0, 0, 1, 1, 1};
  const int dws[8] = {-1, 0, 1,-1, 1,-1, 0, 1};
  int js[8]; unsigned mask = 0;
  #pragma unroll
  for (int t = 0; t < 8; ++t){
    int rr = r + drs[t], ww = w + dws[t];
    bool ok = ((unsigned)rr < 32u) && ((unsigned)ww < 32u);
    int j = (b << 10) + (rr << 5) + ww;
    js[t] = ok ? j : i;
    if (ok && idx[js[t]] != ci) mask |= (1u << t);
  }
  const float4* xr = (const float4*)(x + (size_t)i * C_DIM);
  const float4* cr = (const float4*)(csum + (size_t)ci * C_DIM);
  float4 xs[3], ps[3]; float ssx = 0.f, ssp = 0.f;
  #pragma unroll
  for (int u = 0; u < 3; ++u){
    int c4 = u * 64 + lane;                  // 192 float4 per row
    float4 xv = xr[c4];
    float4 pv = cr[c4];
    #pragma unroll
    for (int t = 0; t < 8; ++t)
      if (mask & (1u << t)){
        float4 nv = ((const float4*)(x + (size_t)js[t] * C_DIM))[c4];
        pv.x += nv.x; pv.y += nv.y; pv.z += nv.z; pv.w += nv.w;
      }
    xs[u] = xv; ps[u] = pv;
    ssx += xv.x*xv.x + xv.y*xv.y + xv.z*xv.z + xv.w*xv.w;
    ssp += pv.x*pv.x + pv.y*pv.y + pv.z*pv.z + pv.w*pv.w;
  }
  #pragma unroll
  for (int m = 32; m; m >>= 1){ ssx += __shfl_xor(ssx, m); ssp += __shfl_xor(ssp, m); }
  float rnx = 1.f / fmaxf(sqrtf(ssx), 1e-12f);
  float rnp = 1.f / fmaxf(sqrtf(ssp), 1e-12f);
  u16x4* Br = (u16x4*)(Bn + (size_t)i * C_DIM);
  u16x4* Ar = (u16x4*)(An + (size_t)i * C_DIM);
  #pragma unroll
  for (int u = 0; u < 3; ++u){
    int c4 = u * 64 + lane;
    u16x4 ob, oa;
    ob[0] = f2bf(xs[u].x * rnx); ob[1] = f2bf(xs[u].y * rnx);
    ob[2] = f2bf(xs[u].z * rnx); ob[3] = f2bf(xs[u].w * rnx);
    oa[0] = f2bf(ps[u].x * rnp); oa[1] = f2bf(ps[u].y * rnp);
    oa[2] = f2bf(ps[u].z * rnp); oa[3] = f2bf(ps[u].w * rnp);
    Br[c4] = ob;
    Ar[c4] = oa;
  }
}

// ---------------- 4/7) bf16 MFMA GEMM, C = A * B^T (A[M,K], B[N,K] row-major) ----------------
// R10-frozen structure: 512 threads (8 waves, 2m x 4n, per-wave 64x32 output, acc[4][2])
// + 2-buffer schedule: STAGE(next) -> compute(cur) -> vmcnt(0) -> s_barrier
// (wait-then-barrier discipline, R8 lesson). 64KB LDS -> 2 blocks/CU = 16 waves/CU.
// (Occupancy ladder: 8->16 waves = -15us (R10); 16->32 = 0 (R11); 3-deep = 0 (R9);
//  setprio <= noise-negative (R12). Structure frozen.)
// MODE 0: grid 1024 = 32m x 32n, K=768, fp16 S out.
// MODE 1: grid 1536 = 32m x 6n x 8z (K-split), K=4096, z == xcd. R14: z=4 -> 8 so
//         1536 blocks / 512 resident slots = exactly 3 fully-PAIRED rounds — removes
//         z=4's solo-block phase (1.5 rounds) that ran at the slow 8-waves/CU regime.
template<int MODE>
__global__ __launch_bounds__(512) void gemm_bt_k(const uint16_t* __restrict__ A, const uint16_t* __restrict__ B,
                                                 int ldA, int ldB, int K,
                                                 _Float16* __restrict__ Sout,
                                                 const float* __restrict__ rden,
                                                 _Float16* __restrict__ Obuf){
  __shared__ __align__(16) char smem[65536];       // 2 x (A 16KB | B 16KB)
  const int g = blockIdx.x;
  const int tid = threadIdx.x;

  const int lane = tid & 63, wid = tid >> 6;
  const int q = lane >> 4, l16 = lane & 15;
  const int wrow = wid & 1, wcol = wid >> 1;       // 2 x 4 waves; per-wave 64 x 32 output

  // ---- XCD swizzle ----
  const int xcd = g & 7;
  const int j   = g >> 3;
  int i0, n0, kt0, per, z = 0;
  const int KT = K >> 6;
  if (MODE == 0){
    int sq = j >> 4;                                  // 0..7: 2x4 grid of 4x4 sub-blocks
    int mi = ((sq >> 2) << 2) + ((j >> 2) & 3);       // 0..7
    int ni = ((sq & 3) << 2) + (j & 3);               // 0..15
    i0 = (((xcd >> 1) << 3) + mi) * 128;              // m in [0,32)
    n0 = (((xcd & 1) << 4) + ni) * 128;               // n in [0,32)
    kt0 = 0; per = KT;                                // per = 12
  } else {
    z  = xcd;                                         // 0..7, one K-slice per XCD (R2-verified)
    i0 = (j / 6) * 128;                               // m in [0,32)
    n0 = (j % 6) * 128;                               // n in [0,6)
    per = KT >> 3; kt0 = z * per;                     // per = 8 K-iters per block
  }

  f32x4 acc[4][2] = {};

  auto STAGE = [&](int c, int kt){                 // 4 gload_lds per thread
    const int k0 = kt << 6;
    char* sb = smem + c * 32768;
    #pragma unroll
    for (int t = 0; t < 2; ++t){
      int p   = t * 512 + tid;                     // [0,1024)
      int row = p >> 3, kc = p & 7;
      int kcs = kc ^ (row & 7);                    // XOR swizzle on the GLOBAL side
      gl2lds16(A + (size_t)(i0 + row) * ldA + k0 + kcs * 8, sb + p * 16);
      gl2lds16(B + (size_t)(n0 + row) * ldB + k0 + kcs * 8, sb + 16384 + p * 16);
    }
  };

  // prologue: fill buffer 0 (wait THEN barrier)
  STAGE(0, kt0);
  asm volatile("s_waitcnt vmcnt(0)" ::: "memory");
  __builtin_amdgcn_s_barrier();

  int cur = 0;
  const int ktEnd = kt0 + per;
  for (int kt = kt0; kt < ktEnd; ++kt){
    if (kt + 1 < ktEnd) STAGE(cur ^ 1, kt + 1);    // prefetch next tile (in flight under MFMA)
    const char* sb = smem + cur * 32768;
    #pragma unroll
    for (int ks = 0; ks < 2; ++ks){
      bf16x8 af[4], bfr[2];
      #pragma unroll
      for (int mt = 0; mt < 4; ++mt){
        int row = wrow * 64 + mt * 16 + l16;
        int ck  = (ks * 4 + q) ^ (row & 7);
        af[mt] = *(const bf16x8*)(sb + row * 128 + ck * 16);
      }
      #pragma unroll
      for (int nt = 0; nt < 2; ++nt){
        int row = wcol * 32 + nt * 16 + l16;
        int ck  = (ks * 4 + q) ^ (row & 7);
        bfr[nt] = *(const bf16x8*)(sb + 16384 + row * 128 + ck * 16);
      }
      #pragma unroll
      for (int mt = 0; mt < 4; ++mt)
        #pragma unroll
        for (int nt = 0; nt < 2; ++nt)
          acc[mt][nt] = __builtin_amdgcn_mfma_f32_16x16x32_bf16(af[mt], bfr[nt], acc[mt][nt], 0, 0, 0);
    }
    asm volatile("s_waitcnt vmcnt(0)" ::: "memory");  // prefetch done (hidden under MFMA)
    __builtin_amdgcn_s_barrier();
    cur ^= 1;
  }

  _Float16* Pz = (MODE == 1) ? (Obuf + (size_t)z * N_TOK * C_DIM) : nullptr;
  #pragma unroll
  for (int mt = 0; mt < 4; ++mt){
    #pragma unroll
    for (int r = 0; r < 4; ++r){
      int row = i0 + wrow * 64 + mt * 16 + q * 4 + r;   // C/D: col=lane&15, row=(lane>>4)*4+reg
      float rd = (MODE == 1) ? rden[row] : 0.f;
      #pragma unroll
      for (int nt = 0; nt < 2; ++nt){
        int col = n0 + wcol * 32 + nt * 16 + l16;
        float v = acc[mt][nt][r];
        if (MODE == 0)
          Sout[(size_t)row * 4096 + col] = (_Float16)v;
        else
          Pz[(size_t)row * C_DIM + col] = (_Float16)(v * rd);
      }
    }
  }
}

// ---------------- 5/6) row stats + cut + exp -> P bf16, 1/denom ----------------
// One row per WAVE (4 rows/block, 1024 blocks). f16x8 loads, shuffle-only reductions.
__global__ __launch_bounds__(256) void rowsoftmax_k(const _Float16* __restrict__ S, uint16_t* __restrict__ P,
                                                    float* __restrict__ rden){
  const int row = blockIdx.x * 4 + (threadIdx.x >> 6);
  const int lane = threadIdx.x & 63;
  const f16x8* Sr = (const f16x8*)(S + (size_t)row * 4096);
  f16x8 h[8];
  #pragma unroll
  for (int c = 0; c < 8; ++c) h[c] = Sr[c * 64 + lane];
  float v[64];
  float mx = -3.4e38f, sm = 0.f;
  #pragma unroll
  for (int c = 0; c < 8; ++c)
    #pragma unroll
    for (int e = 0; e < 8; ++e){
      float f = (float)h[c][e];
      v[c * 8 + e] = f; mx = fmaxf(mx, f); sm += f;
    }
  #pragma unroll
  for (int m = 32; m; m >>= 1){ mx = fmaxf(mx, __shfl_xor(mx, m)); sm += __shfl_xor(sm, m); }

  float bmu  = 1.2f * fmaxf(sm * (1.f / 4096.f), 0.f);
  float amax = 3.0f * (mx - bmu);                 // identical expression to per-element 'a' below
  float cut  = fminf(amax, 0.1f);

  float den = 0.f;
  u16x8 o[8];
  #pragma unroll
  for (int c = 0; c < 8; ++c)
    #pragma unroll
    for (int e = 0; e < 8; ++e){
      float a  = 3.0f * (v[c * 8 + e] - bmu);
      float ev = (a >= cut) ? __expf((a - amax) * (1.f / 0.07f)) : 0.f;
      den += ev;
      o[c][e] = f2bf(ev);
    }
  #pragma unroll
  for (int m = 32; m; m >>= 1) den += __shfl_xor(den, m);
  if (lane == 0) rden[row] = 1.f / den;           // den >= 1 (argmax always kept)

  u16x8* Pr = (u16x8*)(P + (size_t)row * 4096);
  #pragma unroll
  for (int c = 0; c < 8; ++c) Pr[c * 64 + lane] = o[c];
}

// ---------------- 8) z-partial (fp16, pre-scaled) reduction + final layout ----------------
__global__ __launch_bounds__(256) void reduce_k(const _Float16* __restrict__ Pz, float* __restrict__ out){
  const int t = blockIdx.x * 256 + threadIdx.x;   // 8-col unit, 4096*96 total
  const int row = t / 96, c8 = t % 96;
  const size_t base = (size_t)row * C_DIM + c8 * 8;
  const size_t zs = (size_t)N_TOK * C_DIM;
  float o[8] = {0.f, 0.f, 0.f, 0.f, 0.f, 0.f, 0.f, 0.f};
  #pragma unroll
  for (int z = 0; z < ZSPLIT; ++z){
    f16x8 a = *(const f16x8*)(Pz + base + (size_t)z * zs);
    #pragma unroll
    for (int e = 0; e < 8; ++e) o[e] += (float)a[e];
  }
  const int s = row & 1023, bb = row >> 10;       // out[s][b][c]
  float* dst = out + (size_t)s * 3072 + bb * 768 + c8 * 8;
  ((float4*)dst)[0] = make_float4(o[0], o[1], o[2], o[3]);
  ((float4*)dst)[1] = make_float4(o[4], o[5], o[6], o[7]);
}

// ---------------- launcher ----------------
extern "C" void kernel_launch(void* const* d_in, const int* in_sizes, int n_in,
                              void* d_out, int out_size, void* d_ws, size_t ws_size,
                              hipStream_t stream){
  (void)in_sizes; (void)n_in; (void)out_size; (void)ws_size;
  const float* ex   = (const float*)d_in[0];   // [4,1024,768] -> x[4096,768]
  const float* vext = (const float*)d_in[1];   // [48,24,24,64]
  const int*   idx  = (const int*)d_in[2];     // [4096]
  float* out = (float*)d_out;                  // [1024,4,768] fp32
  char* ws = (char*)d_ws;

  // ws layout (~90.3 MB). Time-shared regions:
  //   phase A (gemm1/rowsoftmax): An | Bn | S16 in R
  //   phase B (gemm2/reduce):     Pz fp16 partials 8 x 6.3M = 50.3M in R (exactly fills R)
  uint16_t* P    = (uint16_t*)(ws);                     // 33554432 B
  uint16_t* Vt   = (uint16_t*)(ws + 33554432);          //  6291456 B
  char*     R    = ws + 39845888;                       // 50331648 B region
  uint16_t* An   = (uint16_t*)(R);                      //  6291456 B
  uint16_t* Bn   = (uint16_t*)(R + 6291456);            //  6291456 B
  _Float16* S16  = (_Float16*)(R + 12582912);           // 33554432 B
  _Float16* Pz   = (_Float16*)(R);                      // 50331648 B (aliases An/Bn/S16, phase B)
  float*    csum = (float*)(ws + 90177536);             //    98304 B
  float*    rden = (float*)(ws + 90275840);             //    16384 B

  hipMemsetAsync(csum, 0, NCLU * C_DIM * sizeof(float), stream);
  csum_part_k<<<dim3(128, 3), 256, 0, stream>>>(ex, idx, csum);
  // proxy/key norms (blocks < 1024, XCD-chunked) + fused bilinear resize -> Vt (blocks >= 1024)
  proxy_key_k<<<2560, 256, 0, stream>>>(ex, idx, csum, An, Bn, vext, Vt);
  // S = proxyn @ keyn^T [4096x4096], K=768, fp16 out
  gemm_bt_k<0><<<1024, 512, 0, stream>>>(An, Bn, 768, 768, 768, S16, nullptr, nullptr);
  rowsoftmax_k<<<1024, 256, 0, stream>>>(S16, P, rden);
  // Pz[z] = (softmax(S) @ v) * rden   [4096 x 768], K=4096, K-split x8, fp16 stores
  gemm_bt_k<1><<<1536, 512, 0, stream>>>(P, Vt, 4096, 4096, 4096, nullptr, rden, Pz);
  reduce_k<<<1536, 256, 0, stream>>>(Pz, out);
}

// Round 15
// 177.678 us; speedup vs baseline: 1.0408x; 1.0408x over previous
//
#include <hip/hip_runtime.h>
#include <hip/hip_bf16.h>
#include <stdint.h>

// ---------------- types ----------------
typedef __attribute__((ext_vector_type(8))) short    bf16x8;
typedef __attribute__((ext_vector_type(4))) float    f32x4;
typedef __attribute__((ext_vector_type(8))) unsigned short u16x8;
typedef __attribute__((ext_vector_type(4))) unsigned short u16x4;
typedef __attribute__((ext_vector_type(8))) _Float16 f16x8;

#define N_TOK   4096
#define C_DIM   768
#define NCLU    32
#define ZSPLIT  4

// RNE float->bf16
__device__ __forceinline__ uint16_t f2bf(float f){
  union { float f; unsigned u; } v; v.f = f;
  unsigned r = v.u + 0x7fffu + ((v.u >> 16) & 1u);
  return (uint16_t)(r >> 16);
}

__device__ __forceinline__ void gl2lds16(const void* g, void* l){
  __builtin_amdgcn_global_load_lds(
      (const __attribute__((address_space(1))) unsigned int*)g,
      (__attribute__((address_space(3))) unsigned int*)l, 16, 0, 0);
}

// ---------------- 2) per-cluster sums: LDS accumulate + atomic flush into csum ----------------
__global__ __launch_bounds__(256) void csum_part_k(const float* __restrict__ x, const int* __restrict__ idx,
                                                   float* __restrict__ csum){
  __shared__ float lacc[NCLU * 256];
  __shared__ int   sidx[32];
  const int tc = blockIdx.x, chunk = blockIdx.y;
  const int tid = threadIdx.x;
  #pragma unroll
  for (int u = 0; u < NCLU; ++u) lacc[u * 256 + tid] = 0.f;
  if (tid < 32) sidx[tid] = idx[tc * 32 + tid];
  __syncthreads();
  const int ch = chunk * 256 + tid;
  const float* xb = x + (size_t)(tc * 32) * C_DIM + ch;
  #pragma unroll 8
  for (int t = 0; t < 32; ++t){
    int c = sidx[t];                         // wave-uniform broadcast
    lacc[c * 256 + tid] += xb[(size_t)t * C_DIM];
  }
  __syncthreads();
  float* cb = csum + chunk * 256 + tid;
  #pragma unroll
  for (int c = 0; c < NCLU; ++c) atomicAdd(cb + (size_t)c * C_DIM, lacc[c * 256 + tid]);
}

// ---------------- 3) proxy/key l2norm -> bf16  (+ resize tail, blocks >= 1024) ----------------
// Blocks [0,1024): one token per WAVE (4/block); chunked-XCD remap so each XCD owns a
// contiguous 512-token span -> neighbor-row gathers (i±1, i±32) hit that XCD's L2.
// Blocks [1024,2560): bilinear resize 24x24 -> 32x32 of v_ext into Vt[h*64+d][n] bf16.
__global__ __launch_bounds__(256) void proxy_key_k(const float* __restrict__ x, const int* __restrict__ idx,
                                                   const float* __restrict__ csum,
                                                   uint16_t* __restrict__ An, uint16_t* __restrict__ Bn,
                                                   const float* __restrict__ vext,
                                                   uint16_t* __restrict__ Vt){
  __shared__ float ld[64 * 33];                    // resize scratch (8448 B)
  const int tid = threadIdx.x;

  if (blockIdx.x >= 1024){
    // ---- resize: block rb -> (bh, y) ----
    const int rb = (int)blockIdx.x - 1024, bh = rb >> 5, y = rb & 31;
    const int b = bh / 12, h = bh % 12;
    const float* base = vext + (size_t)bh * 576 * 64;
    float sy = (y + 0.5f) * 0.75f - 0.5f;
    float fy0 = floorf(sy); float fy = sy - fy0; int y0 = (int)fy0;
    int iy0 = y0 < 0 ? 0 : y0;  int iy1 = (y0 + 1 > 23) ? 23 : y0 + 1;
    const int d = tid & 63, xg = tid >> 6;
    #pragma unroll
    for (int jj = 0; jj < 8; ++jj){
      int xx = xg + 4 * jj;
      float sx = (xx + 0.5f) * 0.75f - 0.5f;
      float fx0 = floorf(sx); float fx = sx - fx0; int x0 = (int)fx0;
      int ix0 = x0 < 0 ? 0 : x0;  int ix1 = (x0 + 1 > 23) ? 23 : x0 + 1;
      float v00 = base[(iy0 * 24 + ix0) * 64 + d];
      float v01 = base[(iy0 * 24 + ix1) * 64 + d];
      float v10 = base[(iy1 * 24 + ix0) * 64 + d];
      float v11 = base[(iy1 * 24 + ix1) * 64 + d];
      ld[d * 33 + xx] = (1.f - fy) * ((1.f - fx) * v00 + fx * v01)
                      +        fy  * ((1.f - fx) * v10 + fx * v11);
    }
    __syncthreads();
    const int xx = tid & 31, dg = tid >> 5;
    const int n = b * 1024 + y * 32 + xx;
    #pragma unroll
    for (int jj = 0; jj < 8; ++jj){
      int d2 = dg * 8 + jj;
      Vt[(size_t)(h * 64 + d2) * 4096 + n] = f2bf(ld[d2 * 33 + xx]);
    }
    return;
  }

  const int bid = (int)blockIdx.x;
  const int tb  = ((bid & 7) << 7) + (bid >> 3);   // chunked XCD swizzle (bijective on [0,1024))
  const int i = tb * 4 + (tid >> 6);
  const int lane = tid & 63;
  const int ci = idx[i];
  const int b = i >> 10, s = i & 1023, r = s >> 5, w = s & 31;
  const int drs[8] = {-1,-1,-1, 0, 0, 1, 1, 1};
  const int dws[8] = {-1, 0, 1,-1, 1,-1, 0, 1};
  int js[8]; unsigned mask = 0;
  #pragma unroll
  for (int t = 0; t < 8; ++t){
    int rr = r + drs[t], ww = w + dws[t];
    bool ok = ((unsigned)rr < 32u) && ((unsigned)ww < 32u);
    int j = (b << 10) + (rr << 5) + ww;
    js[t] = ok ? j : i;
    if (ok && idx[js[t]] != ci) mask |= (1u << t);
  }
  const float4* xr = (const float4*)(x + (size_t)i * C_DIM);
  const float4* cr = (const float4*)(csum + (size_t)ci * C_DIM);
  float4 xs[3], ps[3]; float ssx = 0.f, ssp = 0.f;
  #pragma unroll
  for (int u = 0; u < 3; ++u){
    int c4 = u * 64 + lane;                  // 192 float4 per row
    float4 xv = xr[c4];
    float4 pv = cr[c4];
    #pragma unroll
    for (int t = 0; t < 8; ++t)
      if (mask & (1u << t)){
        float4 nv = ((const float4*)(x + (size_t)js[t] * C_DIM))[c4];
        pv.x += nv.x; pv.y += nv.y; pv.z += nv.z; pv.w += nv.w;
      }
    xs[u] = xv; ps[u] = pv;
    ssx += xv.x*xv.x + xv.y*xv.y + xv.z*xv.z + xv.w*xv.w;
    ssp += pv.x*pv.x + pv.y*pv.y + pv.z*pv.z + pv.w*pv.w;
  }
  #pragma unroll
  for (int m = 32; m; m >>= 1){ ssx += __shfl_xor(ssx, m); ssp += __shfl_xor(ssp, m); }
  float rnx = 1.f / fmaxf(sqrtf(ssx), 1e-12f);
  float rnp = 1.f / fmaxf(sqrtf(ssp), 1e-12f);
  u16x4* Br = (u16x4*)(Bn + (size_t)i * C_DIM);
  u16x4* Ar = (u16x4*)(An + (size_t)i * C_DIM);
  #pragma unroll
  for (int u = 0; u < 3; ++u){
    int c4 = u * 64 + lane;
    u16x4 ob, oa;
    ob[0] = f2bf(xs[u].x * rnx); ob[1] = f2bf(xs[u].y * rnx);
    ob[2] = f2bf(xs[u].z * rnx); ob[3] = f2bf(xs[u].w * rnx);
    oa[0] = f2bf(ps[u].x * rnp); oa[1] = f2bf(ps[u].y * rnp);
    oa[2] = f2bf(ps[u].z * rnp); oa[3] = f2bf(ps[u].w * rnp);
    Br[c4] = ob;
    Ar[c4] = oa;
  }
}

// ---------------- 4/7) bf16 MFMA GEMM, C = A * B^T (A[M,K], B[N,K] row-major) ----------------
// SESSION-BEST (R10-exact, 171.7us): 512 threads (8 waves, 2m x 4n, per-wave 64x32
// output, acc[4][2]) + 2-buffer schedule: STAGE(next) -> compute(cur) -> vmcnt(0) ->
// s_barrier (wait-then-barrier discipline, R8 lesson). 64KB LDS -> 2 blocks/CU =
// 16 waves/CU. Final evidence table: occupancy 8->16 waves = -15us (R10);
// 16->32 = null (R11); 3-deep pipeline = null (R9); setprio = noise-neg (R12);
// z=8 = +7us worse (R14). Structure final.
// MODE 0: grid 1024 = 32m x 32n, K=768, fp16 S out.
// MODE 1: grid 768 = 32m x 6n x 4z (K-split), K=4096. fp16 partial*rden stores (no atomics).
template<int MODE>
__global__ __launch_bounds__(512) void gemm_bt_k(const uint16_t* __restrict__ A, const uint16_t* __restrict__ B,
                                                 int ldA, int ldB, int K,
                                                 _Float16* __restrict__ Sout,
                                                 const float* __restrict__ rden,
                                                 _Float16* __restrict__ Obuf){
  __shared__ __align__(16) char smem[65536];       // 2 x (A 16KB | B 16KB)
  const int g = blockIdx.x;
  const int tid = threadIdx.x;

  const int lane = tid & 63, wid = tid >> 6;
  const int q = lane >> 4, l16 = lane & 15;
  const int wrow = wid & 1, wcol = wid >> 1;       // 2 x 4 waves; per-wave 64 x 32 output

  // ---- XCD swizzle ----
  const int xcd = g & 7;
  const int j   = g >> 3;
  int i0, n0, kt0, per, z = 0;
  const int KT = K >> 6;
  if (MODE == 0){
    int sq = j >> 4;                                  // 0..7: 2x4 grid of 4x4 sub-blocks
    int mi = ((sq >> 2) << 2) + ((j >> 2) & 3);       // 0..7
    int ni = ((sq & 3) << 2) + (j & 3);               // 0..15
    i0 = (((xcd >> 1) << 3) + mi) * 128;              // m in [0,32)
    n0 = (((xcd & 1) << 4) + ni) * 128;               // n in [0,32)
    kt0 = 0; per = KT;                                // per = 12
  } else {
    z  = xcd >> 1;                                    // 0..3
    i0 = (((xcd & 1) << 4) + j / 6) * 128;            // m in [0,32)
    n0 = (j % 6) * 128;                               // n in [0,6)
    per = KT >> 2; kt0 = z * per;                     // per = 16
  }

  f32x4 acc[4][2] = {};

  auto STAGE = [&](int c, int kt){                 // 4 gload_lds per thread
    const int k0 = kt << 6;
    char* sb = smem + c * 32768;
    #pragma unroll
    for (int t = 0; t < 2; ++t){
      int p   = t * 512 + tid;                     // [0,1024)
      int row = p >> 3, kc = p & 7;
      int kcs = kc ^ (row & 7);                    // XOR swizzle on the GLOBAL side
      gl2lds16(A + (size_t)(i0 + row) * ldA + k0 + kcs * 8, sb + p * 16);
      gl2lds16(B + (size_t)(n0 + row) * ldB + k0 + kcs * 8, sb + 16384 + p * 16);
    }
  };

  // prologue: fill buffer 0 (wait THEN barrier)
  STAGE(0, kt0);
  asm volatile("s_waitcnt vmcnt(0)" ::: "memory");
  __builtin_amdgcn_s_barrier();

  int cur = 0;
  const int ktEnd = kt0 + per;
  for (int kt = kt0; kt < ktEnd; ++kt){
    if (kt + 1 < ktEnd) STAGE(cur ^ 1, kt + 1);    // prefetch next tile (in flight under MFMA)
    const char* sb = smem + cur * 32768;
    #pragma unroll
    for (int ks = 0; ks < 2; ++ks){
      bf16x8 af[4], bfr[2];
      #pragma unroll
      for (int mt = 0; mt < 4; ++mt){
        int row = wrow * 64 + mt * 16 + l16;
        int ck  = (ks * 4 + q) ^ (row & 7);
        af[mt] = *(const bf16x8*)(sb + row * 128 + ck * 16);
      }
      #pragma unroll
      for (int nt = 0; nt < 2; ++nt){
        int row = wcol * 32 + nt * 16 + l16;
        int ck  = (ks * 4 + q) ^ (row & 7);
        bfr[nt] = *(const bf16x8*)(sb + 16384 + row * 128 + ck * 16);
      }
      #pragma unroll
      for (int mt = 0; mt < 4; ++mt)
        #pragma unroll
        for (int nt = 0; nt < 2; ++nt)
          acc[mt][nt] = __builtin_amdgcn_mfma_f32_16x16x32_bf16(af[mt], bfr[nt], acc[mt][nt], 0, 0, 0);
    }
    asm volatile("s_waitcnt vmcnt(0)" ::: "memory");  // prefetch done (hidden under MFMA)
    __builtin_amdgcn_s_barrier();
    cur ^= 1;
  }

  _Float16* Pz = (MODE == 1) ? (Obuf + (size_t)z * N_TOK * C_DIM) : nullptr;
  #pragma unroll
  for (int mt = 0; mt < 4; ++mt){
    #pragma unroll
    for (int r = 0; r < 4; ++r){
      int row = i0 + wrow * 64 + mt * 16 + q * 4 + r;   // C/D: col=lane&15, row=(lane>>4)*4+reg
      float rd = (MODE == 1) ? rden[row] : 0.f;
      #pragma unroll
      for (int nt = 0; nt < 2; ++nt){
        int col = n0 + wcol * 32 + nt * 16 + l16;
        float v = acc[mt][nt][r];
        if (MODE == 0)
          Sout[(size_t)row * 4096 + col] = (_Float16)v;
        else
          Pz[(size_t)row * C_DIM + col] = (_Float16)(v * rd);
      }
    }
  }
}

// ---------------- 5/6) row stats + cut + exp -> P bf16, 1/denom ----------------
// One row per WAVE (4 rows/block, 1024 blocks). f16x8 loads, shuffle-only reductions.
__global__ __launch_bounds__(256) void rowsoftmax_k(const _Float16* __restrict__ S, uint16_t* __restrict__ P,
                                                    float* __restrict__ rden){
  const int row = blockIdx.x * 4 + (threadIdx.x >> 6);
  const int lane = threadIdx.x & 63;
  const f16x8* Sr = (const f16x8*)(S + (size_t)row * 4096);
  f16x8 h[8];
  #pragma unroll
  for (int c = 0; c < 8; ++c) h[c] = Sr[c * 64 + lane];
  float v[64];
  float mx = -3.4e38f, sm = 0.f;
  #pragma unroll
  for (int c = 0; c < 8; ++c)
    #pragma unroll
    for (int e = 0; e < 8; ++e){
      float f = (float)h[c][e];
      v[c * 8 + e] = f; mx = fmaxf(mx, f); sm += f;
    }
  #pragma unroll
  for (int m = 32; m; m >>= 1){ mx = fmaxf(mx, __shfl_xor(mx, m)); sm += __shfl_xor(sm, m); }

  float bmu  = 1.2f * fmaxf(sm * (1.f / 4096.f), 0.f);
  float amax = 3.0f * (mx - bmu);                 // identical expression to per-element 'a' below
  float cut  = fminf(amax, 0.1f);

  float den = 0.f;
  u16x8 o[8];
  #pragma unroll
  for (int c = 0; c < 8; ++c)
    #pragma unroll
    for (int e = 0; e < 8; ++e){
      float a  = 3.0f * (v[c * 8 + e] - bmu);
      float ev = (a >= cut) ? __expf((a - amax) * (1.f / 0.07f)) : 0.f;
      den += ev;
      o[c][e] = f2bf(ev);
    }
  #pragma unroll
  for (int m = 32; m; m >>= 1) den += __shfl_xor(den, m);
  if (lane == 0) rden[row] = 1.f / den;           // den >= 1 (argmax always kept)

  u16x8* Pr = (u16x8*)(P + (size_t)row * 4096);
  #pragma unroll
  for (int c = 0; c < 8; ++c) Pr[c * 64 + lane] = o[c];
}

// ---------------- 8) z-partial (fp16, pre-scaled) reduction + final layout ----------------
__global__ __launch_bounds__(256) void reduce_k(const _Float16* __restrict__ Pz, float* __restrict__ out){
  const int t = blockIdx.x * 256 + threadIdx.x;   // 8-col unit, 4096*96 total
  const int row = t / 96, c8 = t % 96;
  const size_t base = (size_t)row * C_DIM + c8 * 8;
  const size_t zs = (size_t)N_TOK * C_DIM;
  float o[8] = {0.f, 0.f, 0.f, 0.f, 0.f, 0.f, 0.f, 0.f};
  #pragma unroll
  for (int z = 0; z < ZSPLIT; ++z){
    f16x8 a = *(const f16x8*)(Pz + base + (size_t)z * zs);
    #pragma unroll
    for (int e = 0; e < 8; ++e) o[e] += (float)a[e];
  }
  const int s = row & 1023, bb = row >> 10;       // out[s][b][c]
  float* dst = out + (size_t)s * 3072 + bb * 768 + c8 * 8;
  ((float4*)dst)[0] = make_float4(o[0], o[1], o[2], o[3]);
  ((float4*)dst)[1] = make_float4(o[4], o[5], o[6], o[7]);
}

// ---------------- launcher ----------------
extern "C" void kernel_launch(void* const* d_in, const int* in_sizes, int n_in,
                              void* d_out, int out_size, void* d_ws, size_t ws_size,
                              hipStream_t stream){
  (void)in_sizes; (void)n_in; (void)out_size; (void)ws_size;
  const float* ex   = (const float*)d_in[0];   // [4,1024,768] -> x[4096,768]
  const float* vext = (const float*)d_in[1];   // [48,24,24,64]
  const int*   idx  = (const int*)d_in[2];     // [4096]
  float* out = (float*)d_out;                  // [1024,4,768] fp32
  char* ws = (char*)d_ws;

  // ws layout (~90.3 MB). Time-shared regions:
  //   phase A (gemm1/rowsoftmax): An | Bn | S16 in R
  //   phase B (gemm2/reduce):     Pz fp16 partials 4 x 6.3M = 25.2M in R
  uint16_t* P    = (uint16_t*)(ws);                     // 33554432 B
  uint16_t* Vt   = (uint16_t*)(ws + 33554432);          //  6291456 B
  char*     R    = ws + 39845888;                       // 50331648 B region
  uint16_t* An   = (uint16_t*)(R);                      //  6291456 B
  uint16_t* Bn   = (uint16_t*)(R + 6291456);            //  6291456 B
  _Float16* S16  = (_Float16*)(R + 12582912);           // 33554432 B
  _Float16* Pz   = (_Float16*)(R);                      // 25165824 B (aliases An/Bn/S16 head, phase B)
  float*    csum = (float*)(ws + 90177536);             //    98304 B
  float*    rden = (float*)(ws + 90275840);             //    16384 B

  hipMemsetAsync(csum, 0, NCLU * C_DIM * sizeof(float), stream);
  csum_part_k<<<dim3(128, 3), 256, 0, stream>>>(ex, idx, csum);
  // proxy/key norms (blocks < 1024, XCD-chunked) + fused bilinear resize -> Vt (blocks >= 1024)
  proxy_key_k<<<2560, 256, 0, stream>>>(ex, idx, csum, An, Bn, vext, Vt);
  // S = proxyn @ keyn^T [4096x4096], K=768, fp16 out
  gemm_bt_k<0><<<1024, 512, 0, stream>>>(An, Bn, 768, 768, 768, S16, nullptr, nullptr);
  rowsoftmax_k<<<1024, 256, 0, stream>>>(S16, P, rden);
  // Pz[z] = (softmax(S) @ v) * rden   [4096 x 768], K=4096, K-split x4, fp16 stores
  gemm_bt_k<1><<<768, 512, 0, stream>>>(P, Vt, 4096, 4096, 4096, nullptr, rden, Pz);
  reduce_k<<<1536, 256, 0, stream>>>(Pz, out);
}

// Round 16
// 169.342 us; speedup vs baseline: 1.0921x; 1.0492x over previous
//
#include <hip/hip_runtime.h>
#include <hip/hip_bf16.h>
#include <stdint.h>

// ---------------- types ----------------
typedef __attribute__((ext_vector_type(8))) short    bf16x8;
typedef __attribute__((ext_vector_type(4))) float    f32x4;
typedef __attribute__((ext_vector_type(8))) unsigned short u16x8;
typedef __attribute__((ext_vector_type(4))) unsigned short u16x4;
typedef __attribute__((ext_vector_type(8))) _Float16 f16x8;

#define N_TOK   4096
#define C_DIM   768
#define NCLU    32
#define ZSPLIT  4

// RNE float->bf16
__device__ __forceinline__ uint16_t f2bf(float f){
  union { float f; unsigned u; } v; v.f = f;
  unsigned r = v.u + 0x7fffu + ((v.u >> 16) & 1u);
  return (uint16_t)(r >> 16);
}

__device__ __forceinline__ void gl2lds16(const void* g, void* l){
  __builtin_amdgcn_global_load_lds(
      (const __attribute__((address_space(1))) unsigned int*)g,
      (__attribute__((address_space(3))) unsigned int*)l, 16, 0, 0);
}

// ---------------- 2) per-cluster sums (blocks < 384) + resize tail (blocks >= 384) ----------------
// csum uses only 384 blocks = 1.5/CU — 85% of the machine idle. The bilinear resize
// (no dependency on csum; Vt first consumed by gemm<1>, 3 launches later) is re-homed
// here to fill that idle capacity. Both bodies byte-identical to their verified forms.
__global__ __launch_bounds__(256) void csum_resize_k(const float* __restrict__ x, const int* __restrict__ idx,
                                                     float* __restrict__ csum,
                                                     const float* __restrict__ vext,
                                                     uint16_t* __restrict__ Vt){
  const int tid = threadIdx.x;

  if (blockIdx.x >= 384){
    // ---- resize: block rb -> (bh, y) ----
    __shared__ float ld[64 * 33];                  // resize scratch (8448 B)
    const int rb = (int)blockIdx.x - 384, bh = rb >> 5, y = rb & 31;
    const int b = bh / 12, h = bh % 12;
    const float* base = vext + (size_t)bh * 576 * 64;
    float sy = (y + 0.5f) * 0.75f - 0.5f;
    float fy0 = floorf(sy); float fy = sy - fy0; int y0 = (int)fy0;
    int iy0 = y0 < 0 ? 0 : y0;  int iy1 = (y0 + 1 > 23) ? 23 : y0 + 1;
    const int d = tid & 63, xg = tid >> 6;
    #pragma unroll
    for (int jj = 0; jj < 8; ++jj){
      int xx = xg + 4 * jj;
      float sx = (xx + 0.5f) * 0.75f - 0.5f;
      float fx0 = floorf(sx); float fx = sx - fx0; int x0 = (int)fx0;
      int ix0 = x0 < 0 ? 0 : x0;  int ix1 = (x0 + 1 > 23) ? 23 : x0 + 1;
      float v00 = base[(iy0 * 24 + ix0) * 64 + d];
      float v01 = base[(iy0 * 24 + ix1) * 64 + d];
      float v10 = base[(iy1 * 24 + ix0) * 64 + d];
      float v11 = base[(iy1 * 24 + ix1) * 64 + d];
      ld[d * 33 + xx] = (1.f - fy) * ((1.f - fx) * v00 + fx * v01)
                      +        fy  * ((1.f - fx) * v10 + fx * v11);
    }
    __syncthreads();
    const int xx = tid & 31, dg = tid >> 5;
    const int n = b * 1024 + y * 32 + xx;
    #pragma unroll
    for (int jj = 0; jj < 8; ++jj){
      int d2 = dg * 8 + jj;
      Vt[(size_t)(h * 64 + d2) * 4096 + n] = f2bf(ld[d2 * 33 + xx]);
    }
    return;
  }

  // ---- per-cluster sums: LDS accumulate + atomic flush into csum (pre-zeroed) ----
  __shared__ float lacc[NCLU * 256];
  __shared__ int   sidx[32];
  const int tc = (int)blockIdx.x / 3, chunk = (int)blockIdx.x % 3;
  #pragma unroll
  for (int u = 0; u < NCLU; ++u) lacc[u * 256 + tid] = 0.f;
  if (tid < 32) sidx[tid] = idx[tc * 32 + tid];
  __syncthreads();
  const int ch = chunk * 256 + tid;
  const float* xb = x + (size_t)(tc * 32) * C_DIM + ch;
  #pragma unroll 8
  for (int t = 0; t < 32; ++t){
    int c = sidx[t];                         // wave-uniform broadcast
    lacc[c * 256 + tid] += xb[(size_t)t * C_DIM];
  }
  __syncthreads();
  float* cb = csum + chunk * 256 + tid;
  #pragma unroll
  for (int c = 0; c < NCLU; ++c) atomicAdd(cb + (size_t)c * C_DIM, lacc[c * 256 + tid]);
}

// ---------------- 3) proxy/key l2norm -> bf16 (pure norm pass, 1024 blocks) ----------------
// One token per WAVE (4/block); chunked-XCD remap so each XCD owns a contiguous
// 512-token span -> neighbor-row gathers (i±1, i±32) hit that XCD's L2.
__global__ __launch_bounds__(256) void proxy_key_k(const float* __restrict__ x, const int* __restrict__ idx,
                                                   const float* __restrict__ csum,
                                                   uint16_t* __restrict__ An, uint16_t* __restrict__ Bn){
  const int tid = threadIdx.x;
  const int bid = (int)blockIdx.x;
  const int tb  = ((bid & 7) << 7) + (bid >> 3);   // chunked XCD swizzle (bijective on [0,1024))
  const int i = tb * 4 + (tid >> 6);
  const int lane = tid & 63;
  const int ci = idx[i];
  const int b = i >> 10, s = i & 1023, r = s >> 5, w = s & 31;
  const int drs[8] = {-1,-1,-1, 0, 0, 1, 1, 1};
  const int dws[8] = {-1, 0, 1,-1, 1,-1, 0, 1};
  int js[8]; unsigned mask = 0;
  #pragma unroll
  for (int t = 0; t < 8; ++t){
    int rr = r + drs[t], ww = w + dws[t];
    bool ok = ((unsigned)rr < 32u) && ((unsigned)ww < 32u);
    int j = (b << 10) + (rr << 5) + ww;
    js[t] = ok ? j : i;
    if (ok && idx[js[t]] != ci) mask |= (1u << t);
  }
  const float4* xr = (const float4*)(x + (size_t)i * C_DIM);
  const float4* cr = (const float4*)(csum + (size_t)ci * C_DIM);
  float4 xs[3], ps[3]; float ssx = 0.f, ssp = 0.f;
  #pragma unroll
  for (int u = 0; u < 3; ++u){
    int c4 = u * 64 + lane;                  // 192 float4 per row
    float4 xv = xr[c4];
    float4 pv = cr[c4];
    #pragma unroll
    for (int t = 0; t < 8; ++t)
      if (mask & (1u << t)){
        float4 nv = ((const float4*)(x + (size_t)js[t] * C_DIM))[c4];
        pv.x += nv.x; pv.y += nv.y; pv.z += nv.z; pv.w += nv.w;
      }
    xs[u] = xv; ps[u] = pv;
    ssx += xv.x*xv.x + xv.y*xv.y + xv.z*xv.z + xv.w*xv.w;
    ssp += pv.x*pv.x + pv.y*pv.y + pv.z*pv.z + pv.w*pv.w;
  }
  #pragma unroll
  for (int m = 32; m; m >>= 1){ ssx += __shfl_xor(ssx, m); ssp += __shfl_xor(ssp, m); }
  float rnx = 1.f / fmaxf(sqrtf(ssx), 1e-12f);
  float rnp = 1.f / fmaxf(sqrtf(ssp), 1e-12f);
  u16x4* Br = (u16x4*)(Bn + (size_t)i * C_DIM);
  u16x4* Ar = (u16x4*)(An + (size_t)i * C_DIM);
  #pragma unroll
  for (int u = 0; u < 3; ++u){
    int c4 = u * 64 + lane;
    u16x4 ob, oa;
    ob[0] = f2bf(xs[u].x * rnx); ob[1] = f2bf(xs[u].y * rnx);
    ob[2] = f2bf(xs[u].z * rnx); ob[3] = f2bf(xs[u].w * rnx);
    oa[0] = f2bf(ps[u].x * rnp); oa[1] = f2bf(ps[u].y * rnp);
    oa[2] = f2bf(ps[u].z * rnp); oa[3] = f2bf(ps[u].w * rnp);
    Br[c4] = ob;
    Ar[c4] = oa;
  }
}

// ---------------- 4/7) bf16 MFMA GEMM, C = A * B^T (A[M,K], B[N,K] row-major) ----------------
// SESSION-BEST STRUCTURE (R10-exact, 171.7us): 512 threads (8 waves, 2m x 4n, per-wave
// 64x32 output, acc[4][2]) + 2-buffer schedule: STAGE(next) -> compute(cur) ->
// vmcnt(0) -> s_barrier (wait-then-barrier discipline, R8 lesson). 64KB LDS ->
// 2 blocks/CU = 16 waves/CU. Evidence: occupancy 8->16 waves = -15us (R10);
// 16->32 = null (R11); 3-deep = null (R9); setprio = noise-neg (R12); z=8 = worse (R14).
// MODE 0: grid 1024 = 32m x 32n, K=768, fp16 S out.
// MODE 1: grid 768 = 32m x 6n x 4z (K-split), K=4096. fp16 partial*rden stores (no atomics).
template<int MODE>
__global__ __launch_bounds__(512) void gemm_bt_k(const uint16_t* __restrict__ A, const uint16_t* __restrict__ B,
                                                 int ldA, int ldB, int K,
                                                 _Float16* __restrict__ Sout,
                                                 const float* __restrict__ rden,
                                                 _Float16* __restrict__ Obuf){
  __shared__ __align__(16) char smem[65536];       // 2 x (A 16KB | B 16KB)
  const int g = blockIdx.x;
  const int tid = threadIdx.x;

  const int lane = tid & 63, wid = tid >> 6;
  const int q = lane >> 4, l16 = lane & 15;
  const int wrow = wid & 1, wcol = wid >> 1;       // 2 x 4 waves; per-wave 64 x 32 output

  // ---- XCD swizzle ----
  const int xcd = g & 7;
  const int j   = g >> 3;
  int i0, n0, kt0, per, z = 0;
  const int KT = K >> 6;
  if (MODE == 0){
    int sq = j >> 4;                                  // 0..7: 2x4 grid of 4x4 sub-blocks
    int mi = ((sq >> 2) << 2) + ((j >> 2) & 3);       // 0..7
    int ni = ((sq & 3) << 2) + (j & 3);               // 0..15
    i0 = (((xcd >> 1) << 3) + mi) * 128;              // m in [0,32)
    n0 = (((xcd & 1) << 4) + ni) * 128;               // n in [0,32)
    kt0 = 0; per = KT;                                // per = 12
  } else {
    z  = xcd >> 1;                                    // 0..3
    i0 = (((xcd & 1) << 4) + j / 6) * 128;            // m in [0,32)
    n0 = (j % 6) * 128;                               // n in [0,6)
    per = KT >> 2; kt0 = z * per;                     // per = 16
  }

  f32x4 acc[4][2] = {};

  auto STAGE = [&](int c, int kt){                 // 4 gload_lds per thread
    const int k0 = kt << 6;
    char* sb = smem + c * 32768;
    #pragma unroll
    for (int t = 0; t < 2; ++t){
      int p   = t * 512 + tid;                     // [0,1024)
      int row = p >> 3, kc = p & 7;
      int kcs = kc ^ (row & 7);                    // XOR swizzle on the GLOBAL side
      gl2lds16(A + (size_t)(i0 + row) * ldA + k0 + kcs * 8, sb + p * 16);
      gl2lds16(B + (size_t)(n0 + row) * ldB + k0 + kcs * 8, sb + 16384 + p * 16);
    }
  };

  // prologue: fill buffer 0 (wait THEN barrier)
  STAGE(0, kt0);
  asm volatile("s_waitcnt vmcnt(0)" ::: "memory");
  __builtin_amdgcn_s_barrier();

  int cur = 0;
  const int ktEnd = kt0 + per;
  for (int kt = kt0; kt < ktEnd; ++kt){
    if (kt + 1 < ktEnd) STAGE(cur ^ 1, kt + 1);    // prefetch next tile (in flight under MFMA)
    const char* sb = smem + cur * 32768;
    #pragma unroll
    for (int ks = 0; ks < 2; ++ks){
      bf16x8 af[4], bfr[2];
      #pragma unroll
      for (int mt = 0; mt < 4; ++mt){
        int row = wrow * 64 + mt * 16 + l16;
        int ck  = (ks * 4 + q) ^ (row & 7);
        af[mt] = *(const bf16x8*)(sb + row * 128 + ck * 16);
      }
      #pragma unroll
      for (int nt = 0; nt < 2; ++nt){
        int row = wcol * 32 + nt * 16 + l16;
        int ck  = (ks * 4 + q) ^ (row & 7);
        bfr[nt] = *(const bf16x8*)(sb + 16384 + row * 128 + ck * 16);
      }
      #pragma unroll
      for (int mt = 0; mt < 4; ++mt)
        #pragma unroll
        for (int nt = 0; nt < 2; ++nt)
          acc[mt][nt] = __builtin_amdgcn_mfma_f32_16x16x32_bf16(af[mt], bfr[nt], acc[mt][nt], 0, 0, 0);
    }
    asm volatile("s_waitcnt vmcnt(0)" ::: "memory");  // prefetch done (hidden under MFMA)
    __builtin_amdgcn_s_barrier();
    cur ^= 1;
  }

  _Float16* Pz = (MODE == 1) ? (Obuf + (size_t)z * N_TOK * C_DIM) : nullptr;
  #pragma unroll
  for (int mt = 0; mt < 4; ++mt){
    #pragma unroll
    for (int r = 0; r < 4; ++r){
      int row = i0 + wrow * 64 + mt * 16 + q * 4 + r;   // C/D: col=lane&15, row=(lane>>4)*4+reg
      float rd = (MODE == 1) ? rden[row] : 0.f;
      #pragma unroll
      for (int nt = 0; nt < 2; ++nt){
        int col = n0 + wcol * 32 + nt * 16 + l16;
        float v = acc[mt][nt][r];
        if (MODE == 0)
          Sout[(size_t)row * 4096 + col] = (_Float16)v;
        else
          Pz[(size_t)row * C_DIM + col] = (_Float16)(v * rd);
      }
    }
  }
}

// ---------------- 5/6) row stats + cut + exp -> P bf16, 1/denom ----------------
// One row per WAVE (4 rows/block, 1024 blocks). f16x8 loads, shuffle-only reductions.
__global__ __launch_bounds__(256) void rowsoftmax_k(const _Float16* __restrict__ S, uint16_t* __restrict__ P,
                                                    float* __restrict__ rden){
  const int row = blockIdx.x * 4 + (threadIdx.x >> 6);
  const int lane = threadIdx.x & 63;
  const f16x8* Sr = (const f16x8*)(S + (size_t)row * 4096);
  f16x8 h[8];
  #pragma unroll
  for (int c = 0; c < 8; ++c) h[c] = Sr[c * 64 + lane];
  float v[64];
  float mx = -3.4e38f, sm = 0.f;
  #pragma unroll
  for (int c = 0; c < 8; ++c)
    #pragma unroll
    for (int e = 0; e < 8; ++e){
      float f = (float)h[c][e];
      v[c * 8 + e] = f; mx = fmaxf(mx, f); sm += f;
    }
  #pragma unroll
  for (int m = 32; m; m >>= 1){ mx = fmaxf(mx, __shfl_xor(mx, m)); sm += __shfl_xor(sm, m); }

  float bmu  = 1.2f * fmaxf(sm * (1.f / 4096.f), 0.f);
  float amax = 3.0f * (mx - bmu);                 // identical expression to per-element 'a' below
  float cut  = fminf(amax, 0.1f);

  float den = 0.f;
  u16x8 o[8];
  #pragma unroll
  for (int c = 0; c < 8; ++c)
    #pragma unroll
    for (int e = 0; e < 8; ++e){
      float a  = 3.0f * (v[c * 8 + e] - bmu);
      float ev = (a >= cut) ? __expf((a - amax) * (1.f / 0.07f)) : 0.f;
      den += ev;
      o[c][e] = f2bf(ev);
    }
  #pragma unroll
  for (int m = 32; m; m >>= 1) den += __shfl_xor(den, m);
  if (lane == 0) rden[row] = 1.f / den;           // den >= 1 (argmax always kept)

  u16x8* Pr = (u16x8*)(P + (size_t)row * 4096);
  #pragma unroll
  for (int c = 0; c < 8; ++c) Pr[c * 64 + lane] = o[c];
}

// ---------------- 8) z-partial (fp16, pre-scaled) reduction + final layout ----------------
__global__ __launch_bounds__(256) void reduce_k(const _Float16* __restrict__ Pz, float* __restrict__ out){
  const int t = blockIdx.x * 256 + threadIdx.x;   // 8-col unit, 4096*96 total
  const int row = t / 96, c8 = t % 96;
  const size_t base = (size_t)row * C_DIM + c8 * 8;
  const size_t zs = (size_t)N_TOK * C_DIM;
  float o[8] = {0.f, 0.f, 0.f, 0.f, 0.f, 0.f, 0.f, 0.f};
  #pragma unroll
  for (int z = 0; z < ZSPLIT; ++z){
    f16x8 a = *(const f16x8*)(Pz + base + (size_t)z * zs);
    #pragma unroll
    for (int e = 0; e < 8; ++e) o[e] += (float)a[e];
  }
  const int s = row & 1023, bb = row >> 10;       // out[s][b][c]
  float* dst = out + (size_t)s * 3072 + bb * 768 + c8 * 8;
  ((float4*)dst)[0] = make_float4(o[0], o[1], o[2], o[3]);
  ((float4*)dst)[1] = make_float4(o[4], o[5], o[6], o[7]);
}

// ---------------- launcher ----------------
extern "C" void kernel_launch(void* const* d_in, const int* in_sizes, int n_in,
                              void* d_out, int out_size, void* d_ws, size_t ws_size,
                              hipStream_t stream){
  (void)in_sizes; (void)n_in; (void)out_size; (void)ws_size;
  const float* ex   = (const float*)d_in[0];   // [4,1024,768] -> x[4096,768]
  const float* vext = (const float*)d_in[1];   // [48,24,24,64]
  const int*   idx  = (const int*)d_in[2];     // [4096]
  float* out = (float*)d_out;                  // [1024,4,768] fp32
  char* ws = (char*)d_ws;

  // ws layout (~90.3 MB). Time-shared regions:
  //   phase A (gemm1/rowsoftmax): An | Bn | S16 in R
  //   phase B (gemm2/reduce):     Pz fp16 partials 4 x 6.3M = 25.2M in R
  uint16_t* P    = (uint16_t*)(ws);                     // 33554432 B
  uint16_t* Vt   = (uint16_t*)(ws + 33554432);          //  6291456 B
  char*     R    = ws + 39845888;                       // 50331648 B region
  uint16_t* An   = (uint16_t*)(R);                      //  6291456 B
  uint16_t* Bn   = (uint16_t*)(R + 6291456);            //  6291456 B
  _Float16* S16  = (_Float16*)(R + 12582912);           // 33554432 B
  _Float16* Pz   = (_Float16*)(R);                      // 25165824 B (aliases An/Bn/S16 head, phase B)
  float*    csum = (float*)(ws + 90177536);             //    98304 B
  float*    rden = (float*)(ws + 90275840);             //    16384 B

  hipMemsetAsync(csum, 0, NCLU * C_DIM * sizeof(float), stream);
  // cluster sums (384 blocks) + bilinear resize -> Vt (1536 blocks) in ONE launch:
  // resize fills the 85% of the machine csum leaves idle; no data dependency between them.
  csum_resize_k<<<1920, 256, 0, stream>>>(ex, idx, csum, vext, Vt);
  // proxy/key norms, pure 1024-block pass (XCD-chunked)
  proxy_key_k<<<1024, 256, 0, stream>>>(ex, idx, csum, An, Bn);
  // S = proxyn @ keyn^T [4096x4096], K=768, fp16 out
  gemm_bt_k<0><<<1024, 512, 0, stream>>>(An, Bn, 768, 768, 768, S16, nullptr, nullptr);
  rowsoftmax_k<<<1024, 256, 0, stream>>>(S16, P, rden);
  // Pz[z] = (softmax(S) @ v) * rden   [4096 x 768], K=4096, K-split x4, fp16 stores
  gemm_bt_k<1><<<768, 512, 0, stream>>>(P, Vt, 4096, 4096, 4096, nullptr, rden, Pz);
  reduce_k<<<1536, 256, 0, stream>>>(Pz, out);
}